// Round 7
// baseline (187.543 us; speedup 1.0000x reference)
//
#include <hip/hip_runtime.h>
#include <math.h>

#define BB 4096
#define LL 50
#define NN 50
#define DD 128
#define STR 136    // bf16 LDS row stride in shorts (272 B: odd 4-bank rotation/row)

typedef short bf16x8 __attribute__((ext_vector_type(8)));   // 8 bf16 = 4 VGPRs
typedef float f32x4  __attribute__((ext_vector_type(4)));

static __device__ inline unsigned short f32_to_bf16_rne(float f) {
    unsigned int u = __float_as_uint(f);
    u += 0x7FFFu + ((u >> 16) & 1u);   // round-nearest-even
    return (unsigned short)(u >> 16);
}
static __device__ inline float bf16_to_f32(unsigned short h) {
    return __uint_as_float(((unsigned int)h) << 16);
}

// Combined B fragments for mfma_f32_16x16x32_bf16 over extended K=256:
//   kk 0..3 -> W_seq rows, kk 4..7 -> W_last rows.
// ws[((kk*8+nt)*64+lane)*8+j] = W[(kk&3)*32+(lane>>4)*8+j][nt*16+(lane&15)]
__global__ void prep_w(const float* __restrict__ W_seq,
                       const float* __restrict__ W_last,
                       unsigned short* __restrict__ ws)
{
    int t = blockIdx.x * blockDim.x + threadIdx.x;   // 0..4095
    int lane = t & 63;
    int nt   = (t >> 6) & 7;
    int kk   = t >> 9;
    const float* W = (kk < 4) ? W_seq : W_last;
    int kb = (kk & 3) * 32 + (lane >> 4) * 8;
    int n  = nt * 16 + (lane & 15);
    unsigned short* dst = ws + (size_t)t * 8;
    #pragma unroll
    for (int j = 0; j < 8; ++j)
        dst[j] = f32_to_bf16_rne(W[(kb + j) * DD + n]);
}

// 4096 blocks x 512 threads (8 waves). Wave w owns n-tile w (output cols
// w*16..w*16+15), all m-tiles. Per-thread register budget engineered <=64
// (acc[4]=16 bias-initialized, one A-set=16, in-loop B-frag=4, staging
// 3xfloat4 transient) so __launch_bounds__(512,8) yields 8 waves/SIMD =
// 32 waves/CU — 2x the 16-wave/CU ceiling that pinned rounds 0/4/5 at
// ~52us (R4 counters: HBM 0.87 TB/s, occupancy 36%, latency-bound).
// W_last folded into acc via extended K: kk 4..7 use A = v_n row (same for
// every m), B = W_last — no separate accV accumulator.
__global__ __launch_bounds__(512, 8) void sess_attn(
    const int*   __restrict__ seq_idx,   // [B,L]
    const int*   __restrict__ mask,      // [B,L]
    const float* __restrict__ nodes,     // [B,N,D]
    const float* __restrict__ b_seq,     // [D]
    const float* __restrict__ W_alpha,   // [D]
    const unsigned short* __restrict__ wfrag,  // d_ws, combined B-frags
    float*       __restrict__ out)       // [B*D] v_n, then [B*D] session_graph
{
    const int b    = blockIdx.x;
    const int tid  = threadIdx.x;        // 0..511
    const int lane = tid & 63;
    const int wave = tid >> 6;           // 0..7 = owned n-tile
    const int col  = lane & 15;
    const int quad = lane >> 4;

    __shared__ __align__(16) unsigned short s_nbf[NN * STR];  // 13600 B
    __shared__ float s_alpha[64];
    __shared__ float s_cnt[64];
    __shared__ int   s_last;

    // ---- 1) mask/idx first (oldest vmcnt slots; wave 0 consumes early). ----
    int pm = 0, pi = 0;
    if (tid < 64) {
        pm = (tid < LL) ? mask[b * LL + tid]    : 0;
        pi = (tid < LL) ? seq_idx[b * LL + tid] : 0;
    }

    // ---- 2) stage node tile: 1600 float4 over 512 threads (3.125 each),
    //         convert once to bf16, ds_write. 12-16 transient VGPRs. ----
    const float4* nb4 = (const float4*)(nodes + (size_t)b * (NN * DD));
    float4 v0 = nb4[tid];
    float4 v1 = nb4[tid + 512];
    float4 v2 = nb4[tid + 1024];
    float4 v3;
    if (tid < 64) v3 = nb4[tid + 1536];

    // ---- 3) per-lane epilogue scalars for the owned n-tile. ----
    const int ncol = wave * 16 + col;
    const float bb = b_seq[ncol];
    const float wa = W_alpha[ncol];

    if (tid < 64) { s_alpha[tid] = 0.f; s_cnt[tid] = 0.f; }

    // convert + LDS-write (each idx -> row r=idx>>5, col c=(idx&31)*4 shorts)
    {
        ushort4 h;
        int idx, r, c;
        idx = tid;            r = idx >> 5; c = (idx & 31) * 4;
        h.x = f32_to_bf16_rne(v0.x); h.y = f32_to_bf16_rne(v0.y);
        h.z = f32_to_bf16_rne(v0.z); h.w = f32_to_bf16_rne(v0.w);
        *(ushort4*)&s_nbf[r * STR + c] = h;
        idx = tid + 512;      r = idx >> 5; c = (idx & 31) * 4;
        h.x = f32_to_bf16_rne(v1.x); h.y = f32_to_bf16_rne(v1.y);
        h.z = f32_to_bf16_rne(v1.z); h.w = f32_to_bf16_rne(v1.w);
        *(ushort4*)&s_nbf[r * STR + c] = h;
        idx = tid + 1024;     r = idx >> 5; c = (idx & 31) * 4;
        h.x = f32_to_bf16_rne(v2.x); h.y = f32_to_bf16_rne(v2.y);
        h.z = f32_to_bf16_rne(v2.z); h.w = f32_to_bf16_rne(v2.w);
        *(ushort4*)&s_nbf[r * STR + c] = h;
        if (tid < 64) {
            idx = tid + 1536; r = idx >> 5; c = (idx & 31) * 4;
            h.x = f32_to_bf16_rne(v3.x); h.y = f32_to_bf16_rne(v3.y);
            h.z = f32_to_bf16_rne(v3.z); h.w = f32_to_bf16_rne(v3.w);
            *(ushort4*)&s_nbf[r * STR + c] = h;
        }
    }

    // ---- 4) wave 0: seq_len, last index, count histogram. ----
    if (tid < 64) {
        int mm = pm;
        mm += __shfl_xor(mm, 1);  mm += __shfl_xor(mm, 2);
        mm += __shfl_xor(mm, 4);  mm += __shfl_xor(mm, 8);
        mm += __shfl_xor(mm, 16); mm += __shfl_xor(mm, 32);
        int jl = mm - 1;
        if (jl < 0) jl += LL;                 // JAX negative-index wrap
        int li = __shfl(pi, jl);
        if (tid == 0) s_last = li;
        if (tid < LL && pm) atomicAdd(&s_cnt[pi], (float)pm);
    }

    __syncthreads();   // tile + s_last + s_cnt + s_alpha init visible

    const int last = s_last;

    // v_n output: exact fp32 (row is L2/L3-hot from the tile load).
    if (tid < DD)
        out[(size_t)b * DD + tid] = nodes[(size_t)b * (NN * DD) + last * DD + tid];

    // ---- 5) MFMA, extended K=256: kk 0..3 tile@W_seq, kk 4..7 v_n@W_last.
    //         Bias folded into acc init. 32 MFMAs per wave. ----
    f32x4 acc[4];
    #pragma unroll
    for (int m = 0; m < 4; ++m)
        acc[m] = (f32x4){bb, bb, bb, bb};

    const bf16x8* wsf = (const bf16x8*)wfrag;

    #pragma unroll
    for (int kk = 0; kk < 8; ++kk) {
        const int co = (kk & 3) * 32 + quad * 8;
        bf16x8 bfr = wsf[(size_t)((kk * 8 + wave) * 64 + lane)];
        if (kk < 4) {
            bf16x8 a0, a1, a2, a3;
            {
                int r0 = col, r1 = 16 + col, r2 = 32 + col;
                int r3 = (48 + col > NN - 1) ? (NN - 1) : (48 + col);
                a0 = *(const bf16x8*)&s_nbf[r0 * STR + co];
                a1 = *(const bf16x8*)&s_nbf[r1 * STR + co];
                a2 = *(const bf16x8*)&s_nbf[r2 * STR + co];
                a3 = *(const bf16x8*)&s_nbf[r3 * STR + co];
            }
            acc[0] = __builtin_amdgcn_mfma_f32_16x16x32_bf16(a0, bfr, acc[0], 0, 0, 0);
            acc[1] = __builtin_amdgcn_mfma_f32_16x16x32_bf16(a1, bfr, acc[1], 0, 0, 0);
            acc[2] = __builtin_amdgcn_mfma_f32_16x16x32_bf16(a2, bfr, acc[2], 0, 0, 0);
            acc[3] = __builtin_amdgcn_mfma_f32_16x16x32_bf16(a3, bfr, acc[3], 0, 0, 0);
        } else {
            bf16x8 av = *(const bf16x8*)&s_nbf[last * STR + co];
            acc[0] = __builtin_amdgcn_mfma_f32_16x16x32_bf16(av, bfr, acc[0], 0, 0, 0);
            acc[1] = __builtin_amdgcn_mfma_f32_16x16x32_bf16(av, bfr, acc[1], 0, 0, 0);
            acc[2] = __builtin_amdgcn_mfma_f32_16x16x32_bf16(av, bfr, acc[2], 0, 0, 0);
            acc[3] = __builtin_amdgcn_mfma_f32_16x16x32_bf16(av, bfr, acc[3], 0, 0, 0);
        }
    }

    // ---- 6) epilogue: alpha[row] += sum_{owned cols} sigmoid(x)*W_alpha.
    //         C layout: col = lane&15, row = m*16 + quad*4 + r. ----
    #pragma unroll
    for (int m = 0; m < 4; ++m) {
        float pr[4];
        #pragma unroll
        for (int r = 0; r < 4; ++r) {
            float x = acc[m][r];
            pr[r] = wa / (1.f + __expf(-x));
        }
        #pragma unroll
        for (int r = 0; r < 4; ++r) {
            float vv = pr[r];
            vv += __shfl_xor(vv, 1);
            vv += __shfl_xor(vv, 2);
            vv += __shfl_xor(vv, 4);
            vv += __shfl_xor(vv, 8);
            int row = m * 16 + quad * 4 + r;
            if (col == 0 && row < NN) atomicAdd(&s_alpha[row], vv);
        }
    }
    __syncthreads();   // s_alpha complete (all 8 waves' contributions)

    // ---- 7) session_graph[d] = sum_n cnt[n]*alpha[n]*node_bf16[n][d].
    //         2 independent fma chains; 128 threads. ----
    if (tid < DD) {
        float accA = 0.f, accB = 0.f;
        #pragma unroll 5
        for (int n = 0; n < NN; n += 2) {
            float wA = s_cnt[n]     * s_alpha[n];
            float wB = s_cnt[n + 1] * s_alpha[n + 1];
            accA = fmaf(wA, bf16_to_f32(s_nbf[n * STR + tid]), accA);
            accB = fmaf(wB, bf16_to_f32(s_nbf[(n + 1) * STR + tid]), accB);
        }
        out[(size_t)BB * DD + (size_t)b * DD + tid] = accA + accB;
    }
}

extern "C" void kernel_launch(void* const* d_in, const int* in_sizes, int n_in,
                              void* d_out, int out_size, void* d_ws, size_t ws_size,
                              hipStream_t stream) {
    const int*   seq     = (const int*)  d_in[0];
    const int*   mask    = (const int*)  d_in[1];
    const float* nodes   = (const float*)d_in[2];
    // d_in[3] = batch_size scalar (shapes compile-time fixed)
    const float* W_last  = (const float*)d_in[4];
    const float* W_seq   = (const float*)d_in[5];
    const float* b_seq   = (const float*)d_in[6];
    const float* W_alpha = (const float*)d_in[7];
    float*       out     = (float*)      d_out;

    unsigned short* wsf = (unsigned short*)d_ws;   // 64 KB combined B-fragments

    prep_w<<<16, 256, 0, stream>>>(W_seq, W_last, wsf);
    sess_attn<<<BB, 512, 0, stream>>>(seq, mask, nodes, b_seq, W_alpha, wsf, out);
}

// Round 8
// 186.627 us; speedup vs baseline: 1.0049x; 1.0049x over previous
//
#include <hip/hip_runtime.h>
#include <math.h>

#define BB 4096
#define LL 50
#define NN 50
#define DD 128
#define STR 136    // bf16 LDS row stride in shorts (272 B: odd 4-bank rotation/row)

typedef short bf16x8 __attribute__((ext_vector_type(8)));   // 8 bf16 = 4 VGPRs
typedef float f32x4  __attribute__((ext_vector_type(4)));

static __device__ inline unsigned short f32_to_bf16_rne(float f) {
    unsigned int u = __float_as_uint(f);
    u += 0x7FFFu + ((u >> 16) & 1u);   // round-nearest-even
    return (unsigned short)(u >> 16);
}
static __device__ inline float bf16_to_f32(unsigned short h) {
    return __uint_as_float(((unsigned int)h) << 16);
}

// Combined B fragments for mfma_f32_16x16x32_bf16 over extended K=256:
//   kk 0..3 -> W_seq rows, kk 4..7 -> W_last rows.
// ws[((kk*8+nt)*64+lane)*8+j] = W[(kk&3)*32+(lane>>4)*8+j][nt*16+(lane&15)]
__global__ void prep_w(const float* __restrict__ W_seq,
                       const float* __restrict__ W_last,
                       unsigned short* __restrict__ ws)
{
    int t = blockIdx.x * blockDim.x + threadIdx.x;   // 0..4095
    int lane = t & 63;
    int nt   = (t >> 6) & 7;
    int kk   = t >> 9;
    const float* W = (kk < 4) ? W_seq : W_last;
    int kb = (kk & 3) * 32 + (lane >> 4) * 8;
    int n  = nt * 16 + (lane & 15);
    unsigned short* dst = ws + (size_t)t * 8;
    #pragma unroll
    for (int j = 0; j < 8; ++j)
        dst[j] = f32_to_bf16_rne(W[(kb + j) * DD + n]);
}

// 2048 blocks x 256 threads (4 waves), TWO batches per block.
// Rationale (R7 counters): latency-bound, nothing saturated; the limiter is
// the serial per-block chain x 16 slots/CU. This halves the slots and makes
// each chain cover 2 batches: ALL global loads (both tiles, masks, frags,
// scalars) are issued at t=0; batch1's compute runs with zero memory
// dependencies. bfS preloaded ONCE serves both batches (halves frag L2
// traffic); wave0/wave1 reduce the two masks in parallel; the final
// 50-iter loop and v_n stores use all 256 threads (128 per batch).
__global__ __launch_bounds__(256, 4) void sess_attn(
    const int*   __restrict__ seq_idx,   // [B,L]
    const int*   __restrict__ mask,      // [B,L]
    const float* __restrict__ nodes,     // [B,N,D]
    const float* __restrict__ b_seq,     // [D]
    const float* __restrict__ W_alpha,   // [D]
    const unsigned short* __restrict__ wfrag,  // d_ws, combined B-frags
    float*       __restrict__ out)       // [B*D] v_n, then [B*D] session_graph
{
    const int b0   = blockIdx.x * 2;
    const int b1   = b0 + 1;
    const int tid  = threadIdx.x;
    const int lane = tid & 63;
    const int wave = tid >> 6;
    const int col  = lane & 15;
    const int quad = lane >> 4;

    __shared__ __align__(16) unsigned short s_t0[NN * STR];  // 13600 B
    __shared__ __align__(16) unsigned short s_t1[NN * STR];  // 13600 B
    __shared__ float s_alpha0[64], s_cnt0[64];
    __shared__ float s_alpha1[64], s_cnt1[64];
    __shared__ int   s_last0, s_last1;

    // ---- 1) issue ALL global loads up front. ----
    // masks: wave0 -> b0, wave1 -> b1.
    int pm = 0, pi = 0;
    if (tid < 128) {
        int bb = (wave == 0) ? b0 : b1;
        pm = (lane < LL) ? mask[bb * LL + lane]    : 0;
        pi = (lane < LL) ? seq_idx[bb * LL + lane] : 0;
    }

    const float4* nb0 = (const float4*)(nodes + (size_t)b0 * (NN * DD));
    const float4* nb1 = (const float4*)(nodes + (size_t)b1 * (NN * DD));
    float4 va[6], vb[6], vat, vbt;
    #pragma unroll
    for (int j = 0; j < 6; ++j) va[j] = nb0[tid + j * 256];
    #pragma unroll
    for (int j = 0; j < 6; ++j) vb[j] = nb1[tid + j * 256];
    if (tid < 64) { vat = nb0[1536 + tid]; vbt = nb1[1536 + tid]; }

    // W_seq fragments for this wave's n-tiles {2w,2w+1} (shared by b0,b1).
    const bf16x8* wsf = (const bf16x8*)wfrag;
    bf16x8 bfS[8];
    #pragma unroll
    for (int kk = 0; kk < 4; ++kk)
        #pragma unroll
        for (int j2 = 0; j2 < 2; ++j2)
            bfS[kk * 2 + j2] = wsf[(size_t)((kk * 8 + wave * 2 + j2) * 64 + lane)];

    float bb_r[2], wa_r[2];
    #pragma unroll
    for (int j2 = 0; j2 < 2; ++j2) {
        int n = (wave * 2 + j2) * 16 + col;
        bb_r[j2] = b_seq[n];
        wa_r[j2] = W_alpha[n];
    }

    if (tid < 64)                 { s_alpha0[tid]  = 0.f; s_cnt0[tid]  = 0.f; }
    else if (tid < 128)           { s_alpha1[lane] = 0.f; s_cnt1[lane] = 0.f; }

    // ---- 2) convert + LDS-write both tiles (each element once). ----
    #pragma unroll
    for (int j = 0; j < 6; ++j) {
        int idx = tid + j * 256;
        int r = idx >> 5, c = (idx & 31) * 4;
        ushort4 h;
        h.x = f32_to_bf16_rne(va[j].x); h.y = f32_to_bf16_rne(va[j].y);
        h.z = f32_to_bf16_rne(va[j].z); h.w = f32_to_bf16_rne(va[j].w);
        *(ushort4*)&s_t0[r * STR + c] = h;
        h.x = f32_to_bf16_rne(vb[j].x); h.y = f32_to_bf16_rne(vb[j].y);
        h.z = f32_to_bf16_rne(vb[j].z); h.w = f32_to_bf16_rne(vb[j].w);
        *(ushort4*)&s_t1[r * STR + c] = h;
    }
    if (tid < 64) {
        int idx = 1536 + tid;
        int r = idx >> 5, c = (idx & 31) * 4;
        ushort4 h;
        h.x = f32_to_bf16_rne(vat.x); h.y = f32_to_bf16_rne(vat.y);
        h.z = f32_to_bf16_rne(vat.z); h.w = f32_to_bf16_rne(vat.w);
        *(ushort4*)&s_t0[r * STR + c] = h;
        h.x = f32_to_bf16_rne(vbt.x); h.y = f32_to_bf16_rne(vbt.y);
        h.z = f32_to_bf16_rne(vbt.z); h.w = f32_to_bf16_rne(vbt.w);
        *(ushort4*)&s_t1[r * STR + c] = h;
    }

    // ---- 3) waves 0/1: seq_len, last index, histogram (parallel). ----
    if (tid < 128) {
        int mm = pm;
        mm += __shfl_xor(mm, 1);  mm += __shfl_xor(mm, 2);
        mm += __shfl_xor(mm, 4);  mm += __shfl_xor(mm, 8);
        mm += __shfl_xor(mm, 16); mm += __shfl_xor(mm, 32);
        int jl = mm - 1;
        if (jl < 0) jl += LL;                 // JAX negative-index wrap
        int li = __shfl(pi, jl);
        if (lane == 0) { if (wave == 0) s_last0 = li; else s_last1 = li; }
        if (lane < LL && pm)
            atomicAdd((wave == 0) ? &s_cnt0[pi] : &s_cnt1[pi], (float)pm);
    }

    __syncthreads();   // tiles, s_last*, s_cnt*, alpha inits visible

    const int last0 = s_last0, last1 = s_last1;

    // v_n outputs: exact fp32 (rows are L2-hot from the tile loads).
    if (tid < 128)
        out[(size_t)b0 * DD + tid] =
            nodes[(size_t)b0 * (NN * DD) + last0 * DD + tid];
    else
        out[(size_t)b1 * DD + (tid - 128)] =
            nodes[(size_t)b1 * (NN * DD) + last1 * DD + (tid - 128)];

    const int r0 = col, r1 = 16 + col, r2 = 32 + col;
    const int r3 = (48 + col > NN - 1) ? (NN - 1) : (48 + col);

    // ================= batch 0 =================
    {
        f32x4 acc[4][2], accV[2];
        #pragma unroll
        for (int m = 0; m < 4; ++m)
            #pragma unroll
            for (int j2 = 0; j2 < 2; ++j2)
                acc[m][j2] = (f32x4){0.f, 0.f, 0.f, 0.f};
        #pragma unroll
        for (int j2 = 0; j2 < 2; ++j2)
            accV[j2] = (f32x4){bb_r[j2], bb_r[j2], bb_r[j2], bb_r[j2]};

        #pragma unroll
        for (int kk = 0; kk < 4; ++kk) {
            const int co = kk * 32 + quad * 8;
            bf16x8 a0 = *(const bf16x8*)&s_t0[r0 * STR + co];
            bf16x8 a1 = *(const bf16x8*)&s_t0[r1 * STR + co];
            bf16x8 a2 = *(const bf16x8*)&s_t0[r2 * STR + co];
            bf16x8 a3 = *(const bf16x8*)&s_t0[r3 * STR + co];
            bf16x8 av = *(const bf16x8*)&s_t0[last0 * STR + co];
            #pragma unroll
            for (int j2 = 0; j2 < 2; ++j2) {
                bf16x8 bl = wsf[(size_t)(((kk + 4) * 8 + wave * 2 + j2) * 64 + lane)];
                acc[0][j2] = __builtin_amdgcn_mfma_f32_16x16x32_bf16(a0, bfS[kk * 2 + j2], acc[0][j2], 0, 0, 0);
                acc[1][j2] = __builtin_amdgcn_mfma_f32_16x16x32_bf16(a1, bfS[kk * 2 + j2], acc[1][j2], 0, 0, 0);
                acc[2][j2] = __builtin_amdgcn_mfma_f32_16x16x32_bf16(a2, bfS[kk * 2 + j2], acc[2][j2], 0, 0, 0);
                acc[3][j2] = __builtin_amdgcn_mfma_f32_16x16x32_bf16(a3, bfS[kk * 2 + j2], acc[3][j2], 0, 0, 0);
                accV[j2]   = __builtin_amdgcn_mfma_f32_16x16x32_bf16(av, bl,               accV[j2],   0, 0, 0);
            }
        }

        #pragma unroll
        for (int m = 0; m < 4; ++m) {
            float pr[4] = {0.f, 0.f, 0.f, 0.f};
            #pragma unroll
            for (int j2 = 0; j2 < 2; ++j2) {
                float waj = wa_r[j2];
                #pragma unroll
                for (int r = 0; r < 4; ++r) {
                    float x = acc[m][j2][r] + accV[j2][r];
                    pr[r] = fmaf(1.f / (1.f + __expf(-x)), waj, pr[r]);
                }
            }
            #pragma unroll
            for (int r = 0; r < 4; ++r) {
                float vv = pr[r];
                vv += __shfl_xor(vv, 1);
                vv += __shfl_xor(vv, 2);
                vv += __shfl_xor(vv, 4);
                vv += __shfl_xor(vv, 8);
                int row = m * 16 + quad * 4 + r;
                if (col == 0 && row < NN) atomicAdd(&s_alpha0[row], vv);
            }
        }
    }

    // ================= batch 1 =================
    {
        f32x4 acc[4][2], accV[2];
        #pragma unroll
        for (int m = 0; m < 4; ++m)
            #pragma unroll
            for (int j2 = 0; j2 < 2; ++j2)
                acc[m][j2] = (f32x4){0.f, 0.f, 0.f, 0.f};
        #pragma unroll
        for (int j2 = 0; j2 < 2; ++j2)
            accV[j2] = (f32x4){bb_r[j2], bb_r[j2], bb_r[j2], bb_r[j2]};

        #pragma unroll
        for (int kk = 0; kk < 4; ++kk) {
            const int co = kk * 32 + quad * 8;
            bf16x8 a0 = *(const bf16x8*)&s_t1[r0 * STR + co];
            bf16x8 a1 = *(const bf16x8*)&s_t1[r1 * STR + co];
            bf16x8 a2 = *(const bf16x8*)&s_t1[r2 * STR + co];
            bf16x8 a3 = *(const bf16x8*)&s_t1[r3 * STR + co];
            bf16x8 av = *(const bf16x8*)&s_t1[last1 * STR + co];
            #pragma unroll
            for (int j2 = 0; j2 < 2; ++j2) {
                bf16x8 bl = wsf[(size_t)(((kk + 4) * 8 + wave * 2 + j2) * 64 + lane)];
                acc[0][j2] = __builtin_amdgcn_mfma_f32_16x16x32_bf16(a0, bfS[kk * 2 + j2], acc[0][j2], 0, 0, 0);
                acc[1][j2] = __builtin_amdgcn_mfma_f32_16x16x32_bf16(a1, bfS[kk * 2 + j2], acc[1][j2], 0, 0, 0);
                acc[2][j2] = __builtin_amdgcn_mfma_f32_16x16x32_bf16(a2, bfS[kk * 2 + j2], acc[2][j2], 0, 0, 0);
                acc[3][j2] = __builtin_amdgcn_mfma_f32_16x16x32_bf16(a3, bfS[kk * 2 + j2], acc[3][j2], 0, 0, 0);
                accV[j2]   = __builtin_amdgcn_mfma_f32_16x16x32_bf16(av, bl,               accV[j2],   0, 0, 0);
            }
        }

        #pragma unroll
        for (int m = 0; m < 4; ++m) {
            float pr[4] = {0.f, 0.f, 0.f, 0.f};
            #pragma unroll
            for (int j2 = 0; j2 < 2; ++j2) {
                float waj = wa_r[j2];
                #pragma unroll
                for (int r = 0; r < 4; ++r) {
                    float x = acc[m][j2][r] + accV[j2][r];
                    pr[r] = fmaf(1.f / (1.f + __expf(-x)), waj, pr[r]);
                }
            }
            #pragma unroll
            for (int r = 0; r < 4; ++r) {
                float vv = pr[r];
                vv += __shfl_xor(vv, 1);
                vv += __shfl_xor(vv, 2);
                vv += __shfl_xor(vv, 4);
                vv += __shfl_xor(vv, 8);
                int row = m * 16 + quad * 4 + r;
                if (col == 0 && row < NN) atomicAdd(&s_alpha1[row], vv);
            }
        }
    }

    __syncthreads();   // both alpha arrays complete

    // ---- final: session_graph for both batches, all 256 threads. ----
    {
        const int d  = tid & 127;
        const unsigned short* st = (tid < 128) ? s_t0 : s_t1;
        const float* sc = (tid < 128) ? s_cnt0 : s_cnt1;
        const float* sa = (tid < 128) ? s_alpha0 : s_alpha1;
        const int ob = (tid < 128) ? b0 : b1;
        float accA = 0.f, accB = 0.f;
        #pragma unroll 5
        for (int n = 0; n < NN; n += 2) {
            float wA = sc[n]     * sa[n];
            float wB = sc[n + 1] * sa[n + 1];
            accA = fmaf(wA, bf16_to_f32(st[n * STR + d]), accA);
            accB = fmaf(wB, bf16_to_f32(st[(n + 1) * STR + d]), accB);
        }
        out[(size_t)BB * DD + (size_t)ob * DD + d] = accA + accB;
    }
}

extern "C" void kernel_launch(void* const* d_in, const int* in_sizes, int n_in,
                              void* d_out, int out_size, void* d_ws, size_t ws_size,
                              hipStream_t stream) {
    const int*   seq     = (const int*)  d_in[0];
    const int*   mask    = (const int*)  d_in[1];
    const float* nodes   = (const float*)d_in[2];
    // d_in[3] = batch_size scalar (shapes compile-time fixed)
    const float* W_last  = (const float*)d_in[4];
    const float* W_seq   = (const float*)d_in[5];
    const float* b_seq   = (const float*)d_in[6];
    const float* W_alpha = (const float*)d_in[7];
    float*       out     = (float*)      d_out;

    unsigned short* wsf = (unsigned short*)d_ws;   // 64 KB combined B-fragments

    prep_w<<<16, 256, 0, stream>>>(W_seq, W_last, wsf);
    sess_attn<<<BB / 2, 256, 0, stream>>>(seq, mask, nodes, b_seq, W_alpha, wsf, out);
}